// Round 1
// baseline (1664.657 us; speedup 1.0000x reference)
//
#include <hip/hip_runtime.h>

// out = (sum_k h[k] * S_k) @ x   — COO scatter-add SpMM.
// inputs: x[N,64] f32, h[K] f32, vals[K,E] f32, rows[K,E] i32, cols[K,E] i32
// One 64-lane wave per edge; lane = feature. Gather x[c][:] (coalesced 256B),
// scale by h[k]*vals[e], atomicAdd into out[r][:] (coalesced 256B of HW f32 atomics).

__global__ __launch_bounds__(256) void gtconv_scatter(
    const float* __restrict__ x,
    const float* __restrict__ h,
    const float* __restrict__ vals,
    const int*   __restrict__ rows,
    const int*   __restrict__ cols,
    float*       __restrict__ out,
    int KE, int E)
{
    const int lane = threadIdx.x & 63;
    int wave = (blockIdx.x * blockDim.x + threadIdx.x) >> 6;
    const int nwaves = (gridDim.x * blockDim.x) >> 6;

    for (int e = wave; e < KE; e += nwaves) {
        const int   r = rows[e];
        const int   c = cols[e];
        const float v = vals[e];
        const int   k = e / E;              // tap index (uniform per wave)
        const float w = h[k] * v;
        const float xv = x[(size_t)c * 64 + lane];
        unsafeAtomicAdd(&out[(size_t)r * 64 + lane], xv * w);
    }
}

extern "C" void kernel_launch(void* const* d_in, const int* in_sizes, int n_in,
                              void* d_out, int out_size, void* d_ws, size_t ws_size,
                              hipStream_t stream) {
    const float* x    = (const float*)d_in[0];
    const float* h    = (const float*)d_in[1];
    const float* vals = (const float*)d_in[2];
    const int*   rows = (const int*)d_in[3];
    const int*   cols = (const int*)d_in[4];
    float* out = (float*)d_out;

    const int K  = in_sizes[1];
    const int KE = in_sizes[2];
    const int E  = KE / K;

    // Harness poisons d_out with 0xAA and does not re-zero between replays.
    hipMemsetAsync(out, 0, (size_t)out_size * sizeof(float), stream);

    // 8192 blocks x 256 threads = 32768 waves; grid-stride over 8M edges.
    const int threads = 256;
    const int blocks  = 8192;
    gtconv_scatter<<<blocks, threads, 0, stream>>>(x, h, vals, rows, cols, out, KE, E);
}

// Round 2
// 1603.879 us; speedup vs baseline: 1.0379x; 1.0379x over previous
//
#include <hip/hip_runtime.h>

// out = (sum_k h[k] * S_k) @ x  — COO SpMM via on-device counting sort to CSR.
//
// Round-1 baseline (wave-per-edge f32 atomics) hit the atomic-RMW roofline:
// 512M atomics @ 309 G/s = 1.66 ms, WRITE_SIZE == 8M*256B (full write-through).
// This version removes ALL f32 atomics:
//   A) cnt[r]   = per-row edge counts         (8M int atomics)
//   B) offs     = exclusive scan(cnt)         (1 block, LDS scan)
//   C) payload  = {col, h[k]*val} binned by row (8M int atomics + 8B stores)
//   D) out[r,:] = sum over bucket r           (wave per row, reg accumulate,
//                                              single coalesced 256B store)
//
// ws layout: cnt[N] | offs[N+1] | cursor[N] | pad | payload[KE] (int2)

static __global__ __launch_bounds__(256) void count_kernel(
    const int* __restrict__ rows, int* __restrict__ cnt, int KE)
{
    int i = blockIdx.x * blockDim.x + threadIdx.x;
    int stride = gridDim.x * blockDim.x;
    for (int e = i; e < KE; e += stride)
        atomicAdd(&cnt[rows[e]], 1);
}

static __global__ __launch_bounds__(1024) void scan_kernel(
    const int* __restrict__ cnt, int* __restrict__ offs,
    int* __restrict__ cursor, int n)
{
    __shared__ int sums[1024];
    const int t = threadIdx.x;
    const int chunk = (n + 1023) >> 10;
    const int lo = t * chunk;
    const int hi = min(lo + chunk, n);
    int s = 0;
    for (int i = lo; i < hi; ++i) s += cnt[i];
    sums[t] = s;
    __syncthreads();
    // Hillis-Steele inclusive scan over 1024 partials
    for (int d = 1; d < 1024; d <<= 1) {
        int v = (t >= d) ? sums[t - d] : 0;
        __syncthreads();
        sums[t] += v;
        __syncthreads();
    }
    int run = (t > 0) ? sums[t - 1] : 0;   // exclusive prefix of this chunk
    for (int i = lo; i < hi; ++i) {
        int cv = cnt[i];
        offs[i] = run;
        cursor[i] = run;
        run += cv;
    }
    if (t == 1023) offs[n] = sums[1023];
}

static __global__ __launch_bounds__(256) void scatter_kernel(
    const int*   __restrict__ rows,
    const int*   __restrict__ cols,
    const float* __restrict__ vals,
    const float* __restrict__ h,
    int* __restrict__ cursor,
    int2* __restrict__ payload,
    int KE, int E)
{
    int i = blockIdx.x * blockDim.x + threadIdx.x;
    int stride = gridDim.x * blockDim.x;
    for (int e = i; e < KE; e += stride) {
        int r = rows[e];
        float w = h[e / E] * vals[e];
        int pos = atomicAdd(&cursor[r], 1);
        payload[pos] = make_int2(cols[e], __float_as_int(w));
    }
}

static __global__ __launch_bounds__(256) void spmv_kernel(
    const int*  __restrict__ offs,
    const int2* __restrict__ payload,
    const float* __restrict__ x,
    float* __restrict__ out,
    int n)
{
    const int lane = threadIdx.x & 63;
    int wave = (blockIdx.x * blockDim.x + threadIdx.x) >> 6;
    const int nwaves = (gridDim.x * blockDim.x) >> 6;
    for (int r = wave; r < n; r += nwaves) {
        const int s = offs[r];
        const int e = offs[r + 1];
        float acc0 = 0.f, acc1 = 0.f;   // 2-way ILP on the FMA chain
        int i = s;
        for (; i + 1 < e; i += 2) {
            int2 p0 = payload[i];
            int2 p1 = payload[i + 1];
            acc0 += __int_as_float(p0.y) * x[(size_t)p0.x * 64 + lane];
            acc1 += __int_as_float(p1.y) * x[(size_t)p1.x * 64 + lane];
        }
        if (i < e) {
            int2 p = payload[i];
            acc0 += __int_as_float(p.y) * x[(size_t)p.x * 64 + lane];
        }
        out[(size_t)r * 64 + lane] = acc0 + acc1;
    }
}

// Round-1 fallback if ws is too small (keeps correctness guaranteed).
static __global__ __launch_bounds__(256) void gtconv_scatter(
    const float* __restrict__ x, const float* __restrict__ h,
    const float* __restrict__ vals, const int* __restrict__ rows,
    const int* __restrict__ cols, float* __restrict__ out, int KE, int E)
{
    const int lane = threadIdx.x & 63;
    int wave = (blockIdx.x * blockDim.x + threadIdx.x) >> 6;
    const int nwaves = (gridDim.x * blockDim.x) >> 6;
    for (int e = wave; e < KE; e += nwaves) {
        float w = h[e / E] * vals[e];
        float xv = x[(size_t)cols[e] * 64 + lane];
        unsafeAtomicAdd(&out[(size_t)rows[e] * 64 + lane], xv * w);
    }
}

extern "C" void kernel_launch(void* const* d_in, const int* in_sizes, int n_in,
                              void* d_out, int out_size, void* d_ws, size_t ws_size,
                              hipStream_t stream) {
    const float* x    = (const float*)d_in[0];
    const float* h    = (const float*)d_in[1];
    const float* vals = (const float*)d_in[2];
    const int*   rows = (const int*)d_in[3];
    const int*   cols = (const int*)d_in[4];
    float* out = (float*)d_out;

    const int K  = in_sizes[1];
    const int KE = in_sizes[2];
    const int E  = KE / K;
    const int F  = 64;
    const int N  = in_sizes[0] / F;

    // ws layout
    size_t cnt_off  = 0;
    size_t offs_off = cnt_off  + (size_t)N * 4;
    size_t cur_off  = offs_off + (size_t)(N + 1) * 4;
    size_t pl_off   = (cur_off + (size_t)N * 4 + 7) & ~(size_t)7;
    size_t need     = pl_off + (size_t)KE * 8;

    if (ws_size < need) {
        // fallback: atomic scatter (round-1 kernel)
        hipMemsetAsync(out, 0, (size_t)out_size * sizeof(float), stream);
        gtconv_scatter<<<8192, 256, 0, stream>>>(x, h, vals, rows, cols, out, KE, E);
        return;
    }

    char* ws = (char*)d_ws;
    int*  cnt    = (int*)(ws + cnt_off);
    int*  offs   = (int*)(ws + offs_off);
    int*  cursor = (int*)(ws + cur_off);
    int2* payload = (int2*)(ws + pl_off);

    hipMemsetAsync(cnt, 0, (size_t)N * 4, stream);
    count_kernel<<<4096, 256, 0, stream>>>(rows, cnt, KE);
    scan_kernel<<<1, 1024, 0, stream>>>(cnt, offs, cursor, N);
    scatter_kernel<<<4096, 256, 0, stream>>>(rows, cols, vals, h, cursor, payload, KE, E);
    // one wave per row, 4 waves per block
    int blocks = (N + 3) / 4;
    spmv_kernel<<<blocks, 256, 0, stream>>>(offs, payload, x, out, N);
}